// Round 7
// baseline (547.090 us; speedup 1.0000x reference)
//
#include <hip/hip_runtime.h>
#include <hip/hip_bf16.h>
#include <stdint.h>
#include <math.h>

// ---------------- types / helpers ----------------
typedef __attribute__((ext_vector_type(8))) short bf16x8;   // 8 bf16 in 4 VGPRs
typedef __attribute__((ext_vector_type(4))) float f32x4;

#define AS1 __attribute__((address_space(1)))
#define AS3 __attribute__((address_space(3)))

__device__ __forceinline__ ushort f2bf(float f) {
  union { float f; uint32_t u; } in; in.f = f;
  uint32_t u = in.u;
  uint32_t r = u + 0x7fffu + ((u >> 16) & 1u);   // RNE; inputs finite
  return (ushort)(r >> 16);
}
__device__ __forceinline__ float bf2f(ushort h) {
  union { uint32_t u; float f; } out; out.u = ((uint32_t)h) << 16;
  return out.f;
}

// ---------------- cast f32 -> bf16 (vectorized) ----------------
__global__ __launch_bounds__(256)
void cast_f32_bf16(const float4* __restrict__ in, ushort4* __restrict__ out, int n4) {
  int i = blockIdx.x * blockDim.x + threadIdx.x;
  int stride = gridDim.x * blockDim.x;
  for (; i < n4; i += stride) {
    float4 v = in[i];
    ushort4 o;
    o.x = f2bf(v.x); o.y = f2bf(v.y); o.z = f2bf(v.z); o.w = f2bf(v.w);
    out[i] = o;
  }
}

// ---------------- V (B,LK,D) f32 -> Vt (B,D,LK) bf16 ----------------
__global__ __launch_bounds__(256)
void transpose_cast_v(const float* __restrict__ V, ushort* __restrict__ Vt) {
  __shared__ ushort tile[32][33];                // +1 pad: no bank conflicts
  const int b  = blockIdx.z;
  const int k0 = blockIdx.x * 32;
  const int d0 = blockIdx.y * 32;
  const int tx = threadIdx.x;                    // 0..31
  const int ty = threadIdx.y;                    // 0..7
  const float* Vb = V + ((size_t)b * 1024 + k0) * 1024 + d0;
  #pragma unroll
  for (int r = 0; r < 4; ++r) {
    int k = ty * 4 + r;
    tile[k][tx] = f2bf(Vb[(size_t)k * 1024 + tx]);
  }
  __syncthreads();
  ushort* Vtb = Vt + ((size_t)b * 1024 + d0) * 1024 + k0;
  #pragma unroll
  for (int r = 0; r < 4; ++r) {
    int d = ty * 4 + r;
    Vtb[(size_t)d * 1024 + tx] = tile[tx][d];
  }
}

// ---------------- masked softmax over each (b,q) row of S (bf16 in/out) ----
__global__ __launch_bounds__(256)
void softmax_mask(const ushort* __restrict__ S, ushort* __restrict__ P,
                  const float* __restrict__ mask) {
  const int rowId = blockIdx.x;                  // 0..B*LQ-1
  const int b = rowId >> 10;                     // LQ = 1024
  const ushort4* srow = (const ushort4*)(S + (size_t)rowId * 1024);
  const float4* mrow = (const float4*)(mask + (size_t)b * 1024);
  const int t = threadIdx.x;
  const int wid = t >> 6, lane = t & 63;

  ushort4 sv = srow[t];
  float4 mv = mrow[t];
  float s[4] = {bf2f(sv.x), bf2f(sv.y), bf2f(sv.z), bf2f(sv.w)};
  float m[4] = {mv.x, mv.y, mv.z, mv.w};

  float mx = -INFINITY;
  #pragma unroll
  for (int i = 0; i < 4; ++i) if (m[i] != 0.f) mx = fmaxf(mx, s[i]);
  #pragma unroll
  for (int off = 32; off > 0; off >>= 1)
    mx = fmaxf(mx, __shfl_xor(mx, off));

  __shared__ float wred[4][2];
  if (lane == 0) wred[wid][0] = mx;
  __syncthreads();
  float M = fmaxf(fmaxf(wred[0][0], wred[1][0]), fmaxf(wred[2][0], wred[3][0]));

  float e[4]; float sum = 0.f;
  #pragma unroll
  for (int i = 0; i < 4; ++i) {
    e[i] = (m[i] != 0.f) ? __expf(s[i] - M) : 0.f;
    sum += e[i];
  }
  #pragma unroll
  for (int off = 32; off > 0; off >>= 1)
    sum += __shfl_xor(sum, off);
  if (lane == 0) wred[wid][1] = sum;
  __syncthreads();
  float Z = wred[0][1] + wred[1][1] + wred[2][1] + wred[3][1];
  float inv = (Z > 0.f) ? 1.f / Z : 0.f;

  ushort4 o;
  o.x = f2bf(e[0] * inv); o.y = f2bf(e[1] * inv);
  o.z = f2bf(e[2] * inv); o.w = f2bf(e[3] * inv);
  ((ushort4*)(P + (size_t)rowId * 1024))[t] = o;
}

// ---------------- GEMM 256x256, BK=64, 8 waves, 8-phase counted-vmcnt ------
// C = A(Mx1024,row) * Bt(1024x1024,row)^T.  m201/m248-style schedule:
// per K-tile (BK=64), 4 phases; each phase:
//   {ds_read (12 or 4 b128) ; stage 1 half-tile (2 gload_lds) ; barrier ;
//    lgkmcnt(0)+sched_barrier ; setprio(1) ; 16 MFMA (mi-pair x 4ni x 2ks) ;
//    setprio(0) ; [vmcnt(4) at ph3] ; barrier}
// Stage slots for tile t: ph0/ph1 = A(t+1) halves -> buf^1 (A(t-1) dead);
// ph2/ph3 = B(t+2) halves -> buf cur (B(t) dead after ph0's lgkmcnt(0):
// all 8 B-frags live in VGPRs for the rest of the tile).
// vmcnt(4) at ph3: <=2 newest half-tiles (B(t+2)) outstanding -> A(t+1) and
// B(t+1) guaranteed landed; stage lead >= 3 phases.  Never drains to 0.
// LDS layout & swizzle identical to the round-6 passing kernel (verified):
// [buf][A,B][256 rows x 64 bf16], byte involution y ^= (y>>3)&0x70.
// EPI: 0 -> outBf = bf16(acc*scale)                              (S)
//      1 -> outBf = bf16(bf2f(auxBf) + acc)                      (X = Q + PV)
//      2 -> outBf = bf16(relu(acc + bias[col]))                  (FFN1 -> h)
//      3 -> outF  = acc + bias[col] + bf2f(auxBf)                (FFN2 + residual)
#define MFMA_B16(a, b, c) __builtin_amdgcn_mfma_f32_16x16x32_bf16(a, b, c, 0, 0, 0)

#define CL16(MB, AL0, AL1, AH0, AH1)                                    \
  _Pragma("unroll") for (int ni = 0; ni < 4; ++ni) {                    \
    acc[MB][ni]       = MFMA_B16(AL0, bfr[ni][0], acc[MB][ni]);         \
    acc[(MB) + 1][ni] = MFMA_B16(AH0, bfr[ni][0], acc[(MB) + 1][ni]);   \
    acc[MB][ni]       = MFMA_B16(AL1, bfr[ni][1], acc[MB][ni]);         \
    acc[(MB) + 1][ni] = MFMA_B16(AH1, bfr[ni][1], acc[(MB) + 1][ni]);   \
  }

#define PH_TAIL(MB, AL0, AL1, AH0, AH1, DO_VM)                          \
  __builtin_amdgcn_s_barrier();                                         \
  asm volatile("s_waitcnt lgkmcnt(0)" ::: "memory");                    \
  __builtin_amdgcn_sched_barrier(0);                                    \
  __builtin_amdgcn_s_setprio(1);                                        \
  CL16(MB, AL0, AL1, AH0, AH1);                                         \
  __builtin_amdgcn_s_setprio(0);                                        \
  if (DO_VM) { asm volatile("s_waitcnt vmcnt(4)" ::: "memory"); }       \
  __builtin_amdgcn_s_barrier();

template<int EPI>
__global__ __launch_bounds__(512, 2)
void gemm256(const ushort* __restrict__ A, const ushort* __restrict__ Bt,
             size_t aBatch, size_t bBatch, size_t oBatch,
             float scale,
             ushort* outBf, float* outF, const ushort* auxBf,
             const float* __restrict__ bias)
{
  constexpr int K = 1024, N = 1024, NT = 16;    // K-tiles of 64
  __shared__ ushort lds[2][2][16384];           // [buf][A=0,B=1][256*64] = 128 KiB
  const int t = threadIdx.x;
  const int w = t >> 6, lane = t & 63;
  const int wr = w >> 2, wc = w & 3;            // 2 x 4 waves -> 128x64 per wave
  const int lr16 = lane & 15, kg = lane >> 4;

  // T1: XCD-aware bijective remap (nwg is a multiple of 8 for all our grids)
  const unsigned nx = gridDim.x, ny = gridDim.y;
  unsigned flat = blockIdx.x + nx * (blockIdx.y + ny * blockIdx.z);
  const unsigned nwg = nx * ny * gridDim.z;
  const unsigned cpx = nwg >> 3;
  unsigned nf = (flat & 7u) * cpx + (flat >> 3);
  const unsigned bxi = nf % nx;
  const unsigned rest = nf / nx;
  const unsigned byi = rest % ny;
  const unsigned bz = rest / ny;
  const int m0 = byi * 256, n0 = bxi * 256;

  const char* Ab = (const char*)(A + (size_t)bz * aBatch + (size_t)m0 * K);
  const char* Bb = (const char*)(Bt + (size_t)bz * bBatch + (size_t)n0 * K);

  // staging decode: half h in {0,1} covers rows [h*128, h*128+128); per half
  // each thread stages 2 chunks of 16B.  lds-linear byte within 32KB mat:
  // y = h*16384 + (w*2+i)*1024 + lane*16; unswizzled tile byte
  // tb = y ^ ((y>>3)&0x70); global = (tb>>7)*2048 + (tb&127) + kt*128.
  int gOff[2][2], lOff[2][2];
  #pragma unroll
  for (int h = 0; h < 2; ++h)
    #pragma unroll
    for (int i = 0; i < 2; ++i) {
      int y = h * 16384 + (w * 2 + i) * 1024 + lane * 16;
      int tb = y ^ ((y >> 3) & 0x70);
      gOff[h][i] = (tb >> 7) * 2048 + (tb & 127);
      lOff[h][i] = h * 16384 + (w * 2 + i) * 1024;   // wave-uniform base
    }
  auto STAGE_HALF = [&](int buf, int mat, int h, const char* Gb, int kt) {
    #pragma unroll
    for (int i = 0; i < 2; ++i)
      __builtin_amdgcn_global_load_lds(
        (const AS1 void*)(Gb + gOff[h][i] + kt * 128),
        (AS3 void*)((char*)&lds[buf][mat][0] + lOff[h][i]), 16, 0, 0);
  };

  // fragment reads (swizzled): row = base + mi*16 + lr16 (row&7 = lr16&7),
  // slot(ks) = (ks*4+kg) ^ (lr16&7); byte = row*128 + slot*16.
  const int sl0 = (kg ^ (lr16 & 7)) << 4;
  const int aBase = (wr * 128 + lr16) * 128 + sl0;
  const int bBase = (wc * 64 + lr16) * 128 + sl0;
  auto LDA = [&](int buf, int mi, int ks) -> bf16x8 {
    return *(const bf16x8*)((const char*)&lds[buf][0][0] + ((aBase + mi * 2048) ^ (ks * 64)));
  };
  auto LDB = [&](int buf, int ni, int ks) -> bf16x8 {
    return *(const bf16x8*)((const char*)&lds[buf][1][0] + ((bBase + ni * 2048) ^ (ks * 64)));
  };

  f32x4 acc[8][4];
  #pragma unroll
  for (int i = 0; i < 8; ++i)
    #pragma unroll
    for (int j = 0; j < 4; ++j)
      acc[i][j] = (f32x4){0.f, 0.f, 0.f, 0.f};

  // prologue: A(0),B(0) -> buf0; B(1) -> buf1.  12 loads; vmcnt(4) leaves
  // B(1) in flight with tile 0 fully landed.
  STAGE_HALF(0, 0, 0, Ab, 0); STAGE_HALF(0, 0, 1, Ab, 0);
  STAGE_HALF(0, 1, 0, Bb, 0); STAGE_HALF(0, 1, 1, Bb, 0);
  STAGE_HALF(1, 1, 0, Bb, 1); STAGE_HALF(1, 1, 1, Bb, 1);
  asm volatile("s_waitcnt vmcnt(4)" ::: "memory");
  __builtin_amdgcn_s_barrier();

  #pragma unroll 1
  for (int kt = 0; kt < NT; ++kt) {
    const int cur = kt & 1;
    const int nk1 = kt + 1 < NT ? kt + 1 : NT - 1;   // clamped tails: benign
    const int nk2 = kt + 2 < NT ? kt + 2 : NT - 1;   // dummy re-stages into dead regions
    bf16x8 bfr[4][2];
    // ---- phase 0: mi{0,1}; reads a0,a1 (x2 ks) + all B (8) = 12 ds_reads;
    //               stage A(kt+1) h0 -> buf^1
    bf16x8 p00 = LDA(cur, 0, 0), p01 = LDA(cur, 0, 1);
    bf16x8 p10 = LDA(cur, 1, 0), p11 = LDA(cur, 1, 1);
    #pragma unroll
    for (int ni = 0; ni < 4; ++ni) {
      bfr[ni][0] = LDB(cur, ni, 0);
      bfr[ni][1] = LDB(cur, ni, 1);
    }
    STAGE_HALF(cur ^ 1, 0, 0, Ab, nk1);
    PH_TAIL(0, p00, p01, p10, p11, false)
    // ---- phase 1: mi{2,3}; stage A(kt+1) h1 ----
    p00 = LDA(cur, 2, 0); p01 = LDA(cur, 2, 1);
    p10 = LDA(cur, 3, 0); p11 = LDA(cur, 3, 1);
    STAGE_HALF(cur ^ 1, 0, 1, Ab, nk1);
    PH_TAIL(2, p00, p01, p10, p11, false)
    // ---- phase 2: mi{4,5}; stage B(kt+2) h0 -> buf cur (B(kt) dead) ----
    p00 = LDA(cur, 4, 0); p01 = LDA(cur, 4, 1);
    p10 = LDA(cur, 5, 0); p11 = LDA(cur, 5, 1);
    STAGE_HALF(cur, 1, 0, Bb, nk2);
    PH_TAIL(4, p00, p01, p10, p11, false)
    // ---- phase 3: mi{6,7}; stage B(kt+2) h1; counted vmcnt(4) gate ----
    p00 = LDA(cur, 6, 0); p01 = LDA(cur, 6, 1);
    p10 = LDA(cur, 7, 0); p11 = LDA(cur, 7, 1);
    STAGE_HALF(cur, 1, 1, Bb, nk2);
    PH_TAIL(6, p00, p01, p10, p11, true)
  }

  // epilogue: C/D layout col=lane&15, row=(lane>>4)*4+j  [m89-verified]
  const int lr4 = kg * 4;
  #pragma unroll
  for (int mi = 0; mi < 8; ++mi) {
    #pragma unroll
    for (int ni = 0; ni < 4; ++ni) {
      int row = m0 + wr * 128 + mi * 16 + lr4;
      int col = n0 + wc * 64 + ni * 16 + lr16;
      size_t o = (size_t)bz * oBatch + (size_t)row * N + col;
      f32x4 v = acc[mi][ni];
      #pragma unroll
      for (int j = 0; j < 4; ++j) {
        size_t oo = o + (size_t)j * N;
        float x = v[j];
        if (EPI == 0) {
          outBf[oo] = f2bf(x * scale);
        } else if (EPI == 1) {
          outBf[oo] = f2bf(bf2f(auxBf[oo]) + x);
        } else if (EPI == 2) {
          float h = x + bias[col];
          h = h > 0.f ? h : 0.f;
          outBf[oo] = f2bf(h);
        } else {
          outF[oo] = x + bias[col] + bf2f(auxBf[oo]);
        }
      }
    }
  }
}

// ---------------- launch ----------------
extern "C" void kernel_launch(void* const* d_in, const int* in_sizes, int n_in,
                              void* d_out, int out_size, void* d_ws, size_t ws_size,
                              hipStream_t stream) {
  (void)in_sizes; (void)n_in; (void)out_size; (void)ws_size;
  const float* Q  = (const float*)d_in[0];
  const float* Km = (const float*)d_in[1];
  const float* V  = (const float*)d_in[2];
  const float* Vm = (const float*)d_in[3];
  const float* W1 = (const float*)d_in[4];
  const float* b1 = (const float*)d_in[5];
  const float* W2 = (const float*)d_in[6];
  const float* b2 = (const float*)d_in[7];
  float* out = (float*)d_out;

  const int LQ = 1024, LK = 1024, D = 1024;
  const size_t NQ = (size_t)32 * LQ * D;            // 33.5M elems

  // workspace layout (MiB offsets): Qb 0..64, Kb/hb 64..128, Vt 128..192,
  // Sb 192..256, P 256..320, Xb 320..384, W1b 384..386, W2b 386..388
  char* ws = (char*)d_ws;
  ushort* Qb  = (ushort*)(ws);
  ushort* Kb  = (ushort*)(ws + ((size_t)64 << 20));
  ushort* hb  = Kb;                                  // reuse (Kb dead after S-GEMM)
  ushort* Vt  = (ushort*)(ws + ((size_t)128 << 20));
  ushort* Sb  = (ushort*)(ws + ((size_t)192 << 20));
  ushort* P   = (ushort*)(ws + ((size_t)256 << 20));
  ushort* Xb  = (ushort*)(ws + ((size_t)320 << 20));
  ushort* W1b = (ushort*)(ws + ((size_t)384 << 20));
  ushort* W2b = (ushort*)(ws + ((size_t)386 << 20));

  const float inv_scale = 1.0f / (sqrtf(1024.0f) + 1e-8f);

  cast_f32_bf16<<<2048, 256, 0, stream>>>((const float4*)Q,  (ushort4*)Qb, (int)(NQ / 4));
  cast_f32_bf16<<<2048, 256, 0, stream>>>((const float4*)Km, (ushort4*)Kb, (int)(NQ / 4));
  cast_f32_bf16<<<256, 256, 0, stream>>>((const float4*)W1, (ushort4*)W1b, (1024 * 1024) / 4);
  cast_f32_bf16<<<256, 256, 0, stream>>>((const float4*)W2, (ushort4*)W2b, (1024 * 1024) / 4);
  transpose_cast_v<<<dim3(32, 32, 32), dim3(32, 8), 0, stream>>>(V, Vt);

  // Sb = bf16((Qb @ Kb^T) * inv_scale), batched over 32
  gemm256<0><<<dim3(4, 4, 32), 512, 0, stream>>>(
      Qb, Kb,
      (size_t)LQ * D, (size_t)LK * D, (size_t)LQ * LK,
      inv_scale, Sb, nullptr, nullptr, nullptr);

  softmax_mask<<<32768, 256, 0, stream>>>(Sb, P, Vm);

  // Xb = bf16(Qb + P @ V)
  gemm256<1><<<dim3(4, 4, 32), 512, 0, stream>>>(
      P, Vt,
      (size_t)LQ * LK, (size_t)D * LK, (size_t)LQ * D,
      1.f, Xb, nullptr, Qb, nullptr);

  // hb = bf16(relu(Xb @ W1^T + b1)); M = 32768 folded into blockIdx.y
  gemm256<2><<<dim3(4, 128, 1), 512, 0, stream>>>(
      Xb, W1b, 0, 0, 0,
      1.f, hb, nullptr, nullptr, b1);

  // out = hb @ W2^T + b2 + Xb
  gemm256<3><<<dim3(4, 128, 1), 512, 0, stream>>>(
      hb, W2b, 0, 0, 0,
      1.f, nullptr, out, Xb, b2);
}

// Round 8
// 546.965 us; speedup vs baseline: 1.0002x; 1.0002x over previous
//
#include <hip/hip_runtime.h>
#include <hip/hip_bf16.h>
#include <stdint.h>
#include <math.h>

// ---------------- types / helpers ----------------
typedef __attribute__((ext_vector_type(8))) short bf16x8;   // 8 bf16 in 4 VGPRs
typedef __attribute__((ext_vector_type(4))) float f32x4;

#define AS1 __attribute__((address_space(1)))
#define AS3 __attribute__((address_space(3)))

__device__ __forceinline__ ushort f2bf(float f) {
  union { float f; uint32_t u; } in; in.f = f;
  uint32_t u = in.u;
  uint32_t r = u + 0x7fffu + ((u >> 16) & 1u);   // RNE; inputs finite
  return (ushort)(r >> 16);
}
__device__ __forceinline__ float bf2f(ushort h) {
  union { uint32_t u; float f; } out; out.u = ((uint32_t)h) << 16;
  return out.f;
}

// ---------------- cast f32 -> bf16 (vectorized) ----------------
__global__ __launch_bounds__(256)
void cast_f32_bf16(const float4* __restrict__ in, ushort4* __restrict__ out, int n4) {
  int i = blockIdx.x * blockDim.x + threadIdx.x;
  int stride = gridDim.x * blockDim.x;
  for (; i < n4; i += stride) {
    float4 v = in[i];
    ushort4 o;
    o.x = f2bf(v.x); o.y = f2bf(v.y); o.z = f2bf(v.z); o.w = f2bf(v.w);
    out[i] = o;
  }
}

// ---------------- V (B,LK,D) f32 -> Vt (B,D,LK) bf16 ----------------
__global__ __launch_bounds__(256)
void transpose_cast_v(const float* __restrict__ V, ushort* __restrict__ Vt) {
  __shared__ ushort tile[32][33];                // +1 pad: no bank conflicts
  const int b  = blockIdx.z;
  const int k0 = blockIdx.x * 32;
  const int d0 = blockIdx.y * 32;
  const int tx = threadIdx.x;                    // 0..31
  const int ty = threadIdx.y;                    // 0..7
  const float* Vb = V + ((size_t)b * 1024 + k0) * 1024 + d0;
  #pragma unroll
  for (int r = 0; r < 4; ++r) {
    int k = ty * 4 + r;
    tile[k][tx] = f2bf(Vb[(size_t)k * 1024 + tx]);
  }
  __syncthreads();
  ushort* Vtb = Vt + ((size_t)b * 1024 + d0) * 1024 + k0;
  #pragma unroll
  for (int r = 0; r < 4; ++r) {
    int d = ty * 4 + r;
    Vtb[(size_t)d * 1024 + tx] = tile[tx][d];
  }
}

// ---------------- masked softmax over each (b,q) row of S (bf16 in/out) ----
__global__ __launch_bounds__(256)
void softmax_mask(const ushort* __restrict__ S, ushort* __restrict__ P,
                  const float* __restrict__ mask) {
  const int rowId = blockIdx.x;                  // 0..B*LQ-1
  const int b = rowId >> 10;                     // LQ = 1024
  const ushort4* srow = (const ushort4*)(S + (size_t)rowId * 1024);
  const float4* mrow = (const float4*)(mask + (size_t)b * 1024);
  const int t = threadIdx.x;
  const int wid = t >> 6, lane = t & 63;

  ushort4 sv = srow[t];
  float4 mv = mrow[t];
  float s[4] = {bf2f(sv.x), bf2f(sv.y), bf2f(sv.z), bf2f(sv.w)};
  float m[4] = {mv.x, mv.y, mv.z, mv.w};

  float mx = -INFINITY;
  #pragma unroll
  for (int i = 0; i < 4; ++i) if (m[i] != 0.f) mx = fmaxf(mx, s[i]);
  #pragma unroll
  for (int off = 32; off > 0; off >>= 1)
    mx = fmaxf(mx, __shfl_xor(mx, off));

  __shared__ float wred[4][2];
  if (lane == 0) wred[wid][0] = mx;
  __syncthreads();
  float M = fmaxf(fmaxf(wred[0][0], wred[1][0]), fmaxf(wred[2][0], wred[3][0]));

  float e[4]; float sum = 0.f;
  #pragma unroll
  for (int i = 0; i < 4; ++i) {
    e[i] = (m[i] != 0.f) ? __expf(s[i] - M) : 0.f;
    sum += e[i];
  }
  #pragma unroll
  for (int off = 32; off > 0; off >>= 1)
    sum += __shfl_xor(sum, off);
  if (lane == 0) wred[wid][1] = sum;
  __syncthreads();
  float Z = wred[0][1] + wred[1][1] + wred[2][1] + wred[3][1];
  float inv = (Z > 0.f) ? 1.f / Z : 0.f;

  ushort4 o;
  o.x = f2bf(e[0] * inv); o.y = f2bf(e[1] * inv);
  o.z = f2bf(e[2] * inv); o.w = f2bf(e[3] * inv);
  ((ushort4*)(P + (size_t)rowId * 1024))[t] = o;
}

// ---------------- GEMM 256x256, BK=64, 8 waves, 2-phase double-buffer ------
// C = A(Mx1024,row) * Bt(1024x1024,row)^T.  m248 minimum-2-phase recipe,
// WITHOUT the lgkmcnt(0)/sched_barrier fences between ds_read and MFMA:
// the reads are plain C++ loads, so the compiler inserts fine-grained
// lgkmcnt(N) itself (m97 evidence) and may software-pipeline reads with
// MFMAs within the tile.  Per K-tile of 64:
//   STAGE(buf^1, kt+1)  [8 x global_load_lds w=16, issued FIRST]
//   for ks in {0,1}: 12 ds_read_b128 -> 32 MFMA (setprio-wrapped)
//   vmcnt(0) -> barrier -> cur^=1      (one barrier per K-tile)
// Cross-wave safety: every wave's ds_reads are drained before its MFMAs
// issue (dataflow), MFMAs precede the barrier, and next-tile stage-writes
// land only after the barrier -> no read/overwrite race.
// LDS 128 KiB: [2 bufs][A,B][256 rows x 64 bf16].  Rows are 128 B.
// T2 swizzle: byte involution y ^= (y>>3)&0x70 (rule #21 pairing).
// EPI: 0 -> outBf = bf16(acc*scale)                              (S)
//      1 -> outBf = bf16(bf2f(auxBf) + acc)                      (X = Q + PV)
//      2 -> outBf = bf16(relu(acc + bias[col]))                  (FFN1 -> h)
//      3 -> outF  = acc + bias[col] + bf2f(auxBf)                (FFN2 + residual)
template<int EPI>
__global__ __launch_bounds__(512, 2)
void gemm256(const ushort* __restrict__ A, const ushort* __restrict__ Bt,
             size_t aBatch, size_t bBatch, size_t oBatch,
             float scale,
             ushort* outBf, float* outF, const ushort* auxBf,
             const float* __restrict__ bias)
{
  constexpr int K = 1024, N = 1024, NT = 16;    // K-tiles of 64
  __shared__ ushort lds[2][2][16384];           // [buf][A=0,B=1][256*64] = 128 KiB
  const int t = threadIdx.x;
  const int w = t >> 6, lane = t & 63;
  const int wr = w >> 2, wc = w & 3;            // 2 x 4 waves -> 128x64 per wave
  const int lr16 = lane & 15, kg = lane >> 4;

  // T1: XCD-aware bijective remap (nwg is a multiple of 8 for all our grids)
  const unsigned nx = gridDim.x, ny = gridDim.y;
  unsigned flat = blockIdx.x + nx * (blockIdx.y + ny * blockIdx.z);
  const unsigned nwg = nx * ny * gridDim.z;
  const unsigned cpx = nwg >> 3;
  unsigned nf = (flat & 7u) * cpx + (flat >> 3);
  const unsigned bxi = nf % nx;
  const unsigned rest = nf / nx;
  const unsigned byi = rest % ny;
  const unsigned bz = rest / ny;
  const int m0 = byi * 256, n0 = bxi * 256;

  const char* Ab = (const char*)(A + (size_t)bz * aBatch + (size_t)m0 * K);
  const char* Bb = (const char*)(Bt + (size_t)bz * bBatch + (size_t)n0 * K);

  // staging decode: 4 chunks of 16B/lane per matrix per thread.
  // lds-linear byte y = (w*4+i)*1024 + lane*16; unswizzled tile byte
  // tb = y ^ ((y>>3)&0x70); global = (tb>>7)*2048 + (tb&127) + kt*128.
  int gOff[4], lOff[4];
  #pragma unroll
  for (int i = 0; i < 4; ++i) {
    int y = (w * 4 + i) * 1024 + lane * 16;
    int tb = y ^ ((y >> 3) & 0x70);
    gOff[i] = (tb >> 7) * 2048 + (tb & 127);
    lOff[i] = (w * 4 + i) * 1024;               // wave-uniform LDS base (+lane*16 by HW)
  }
  auto STAGE = [&](int buf, int matc, const char* Gb, int kt) {
    #pragma unroll
    for (int i = 0; i < 4; ++i)
      __builtin_amdgcn_global_load_lds(
        (const AS1 void*)(Gb + gOff[i] + kt * 128),
        (AS3 void*)((char*)&lds[buf][matc][0] + lOff[i]), 16, 0, 0);
  };

  // fragment reads (swizzled): row = base + mi*16 + lr16 (row&7 = lr16&7),
  // slot(ks) = (ks*4+kg) ^ (lr16&7); byte = row*128 + slot*16.
  const int sl0 = (kg ^ (lr16 & 7)) << 4;
  const int aBase = (wr * 128 + lr16) * 128 + sl0;
  const int bBase = (wc * 64 + lr16) * 128 + sl0;
  auto LDA = [&](int buf, int mi, int ks) -> bf16x8 {
    return *(const bf16x8*)((const char*)&lds[buf][0][0] + ((aBase + mi * 2048) ^ (ks * 64)));
  };
  auto LDB = [&](int buf, int ni, int ks) -> bf16x8 {
    return *(const bf16x8*)((const char*)&lds[buf][1][0] + ((bBase + ni * 2048) ^ (ks * 64)));
  };

  f32x4 acc[8][4];
  #pragma unroll
  for (int i = 0; i < 8; ++i)
    #pragma unroll
    for (int j = 0; j < 4; ++j)
      acc[i][j] = (f32x4){0.f, 0.f, 0.f, 0.f};

  // prologue: stage tile 0 into buf0, drain, barrier
  STAGE(0, 0, Ab, 0);
  STAGE(0, 1, Bb, 0);
  asm volatile("s_waitcnt vmcnt(0)" ::: "memory");
  __builtin_amdgcn_s_barrier();

  int cur = 0;
  #pragma unroll 1
  for (int kt = 0; kt < NT; ++kt) {
    // issue next-tile staging FIRST (hides under this tile's 64 MFMAs)
    int nk = kt + 1 < NT ? kt + 1 : NT - 1;     // last iter: benign dummy re-stage
    STAGE(cur ^ 1, 0, Ab, nk);
    STAGE(cur ^ 1, 1, Bb, nk);
    #pragma unroll
    for (int ks = 0; ks < 2; ++ks) {
      bf16x8 af0 = LDA(cur, 0, ks), af1 = LDA(cur, 1, ks);
      bf16x8 af2 = LDA(cur, 2, ks), af3 = LDA(cur, 3, ks);
      bf16x8 af4 = LDA(cur, 4, ks), af5 = LDA(cur, 5, ks);
      bf16x8 af6 = LDA(cur, 6, ks), af7 = LDA(cur, 7, ks);
      bf16x8 bf0 = LDB(cur, 0, ks), bf1 = LDB(cur, 1, ks);
      bf16x8 bf2 = LDB(cur, 2, ks), bf3 = LDB(cur, 3, ks);
      // NO lgkmcnt(0)/sched_barrier fence here: compiler inserts fine-grained
      // lgkmcnt(N) per dataflow and may interleave reads with MFMAs.
      __builtin_amdgcn_s_setprio(1);
      acc[0][0] = __builtin_amdgcn_mfma_f32_16x16x32_bf16(af0, bf0, acc[0][0], 0, 0, 0);
      acc[0][1] = __builtin_amdgcn_mfma_f32_16x16x32_bf16(af0, bf1, acc[0][1], 0, 0, 0);
      acc[0][2] = __builtin_amdgcn_mfma_f32_16x16x32_bf16(af0, bf2, acc[0][2], 0, 0, 0);
      acc[0][3] = __builtin_amdgcn_mfma_f32_16x16x32_bf16(af0, bf3, acc[0][3], 0, 0, 0);
      acc[1][0] = __builtin_amdgcn_mfma_f32_16x16x32_bf16(af1, bf0, acc[1][0], 0, 0, 0);
      acc[1][1] = __builtin_amdgcn_mfma_f32_16x16x32_bf16(af1, bf1, acc[1][1], 0, 0, 0);
      acc[1][2] = __builtin_amdgcn_mfma_f32_16x16x32_bf16(af1, bf2, acc[1][2], 0, 0, 0);
      acc[1][3] = __builtin_amdgcn_mfma_f32_16x16x32_bf16(af1, bf3, acc[1][3], 0, 0, 0);
      acc[2][0] = __builtin_amdgcn_mfma_f32_16x16x32_bf16(af2, bf0, acc[2][0], 0, 0, 0);
      acc[2][1] = __builtin_amdgcn_mfma_f32_16x16x32_bf16(af2, bf1, acc[2][1], 0, 0, 0);
      acc[2][2] = __builtin_amdgcn_mfma_f32_16x16x32_bf16(af2, bf2, acc[2][2], 0, 0, 0);
      acc[2][3] = __builtin_amdgcn_mfma_f32_16x16x32_bf16(af2, bf3, acc[2][3], 0, 0, 0);
      acc[3][0] = __builtin_amdgcn_mfma_f32_16x16x32_bf16(af3, bf0, acc[3][0], 0, 0, 0);
      acc[3][1] = __builtin_amdgcn_mfma_f32_16x16x32_bf16(af3, bf1, acc[3][1], 0, 0, 0);
      acc[3][2] = __builtin_amdgcn_mfma_f32_16x16x32_bf16(af3, bf2, acc[3][2], 0, 0, 0);
      acc[3][3] = __builtin_amdgcn_mfma_f32_16x16x32_bf16(af3, bf3, acc[3][3], 0, 0, 0);
      acc[4][0] = __builtin_amdgcn_mfma_f32_16x16x32_bf16(af4, bf0, acc[4][0], 0, 0, 0);
      acc[4][1] = __builtin_amdgcn_mfma_f32_16x16x32_bf16(af4, bf1, acc[4][1], 0, 0, 0);
      acc[4][2] = __builtin_amdgcn_mfma_f32_16x16x32_bf16(af4, bf2, acc[4][2], 0, 0, 0);
      acc[4][3] = __builtin_amdgcn_mfma_f32_16x16x32_bf16(af4, bf3, acc[4][3], 0, 0, 0);
      acc[5][0] = __builtin_amdgcn_mfma_f32_16x16x32_bf16(af5, bf0, acc[5][0], 0, 0, 0);
      acc[5][1] = __builtin_amdgcn_mfma_f32_16x16x32_bf16(af5, bf1, acc[5][1], 0, 0, 0);
      acc[5][2] = __builtin_amdgcn_mfma_f32_16x16x32_bf16(af5, bf2, acc[5][2], 0, 0, 0);
      acc[5][3] = __builtin_amdgcn_mfma_f32_16x16x32_bf16(af5, bf3, acc[5][3], 0, 0, 0);
      acc[6][0] = __builtin_amdgcn_mfma_f32_16x16x32_bf16(af6, bf0, acc[6][0], 0, 0, 0);
      acc[6][1] = __builtin_amdgcn_mfma_f32_16x16x32_bf16(af6, bf1, acc[6][1], 0, 0, 0);
      acc[6][2] = __builtin_amdgcn_mfma_f32_16x16x32_bf16(af6, bf2, acc[6][2], 0, 0, 0);
      acc[6][3] = __builtin_amdgcn_mfma_f32_16x16x32_bf16(af6, bf3, acc[6][3], 0, 0, 0);
      acc[7][0] = __builtin_amdgcn_mfma_f32_16x16x32_bf16(af7, bf0, acc[7][0], 0, 0, 0);
      acc[7][1] = __builtin_amdgcn_mfma_f32_16x16x32_bf16(af7, bf1, acc[7][1], 0, 0, 0);
      acc[7][2] = __builtin_amdgcn_mfma_f32_16x16x32_bf16(af7, bf2, acc[7][2], 0, 0, 0);
      acc[7][3] = __builtin_amdgcn_mfma_f32_16x16x32_bf16(af7, bf3, acc[7][3], 0, 0, 0);
      __builtin_amdgcn_s_setprio(0);
    }
    // stage for tile kt+1 must have fully landed before next iter's ds_reads
    asm volatile("s_waitcnt vmcnt(0)" ::: "memory");
    __builtin_amdgcn_s_barrier();
    cur ^= 1;
  }

  // epilogue: C/D layout col=lane&15, row=(lane>>4)*4+j  [m89-verified]
  const int lr4 = kg * 4;
  #pragma unroll
  for (int mi = 0; mi < 8; ++mi) {
    #pragma unroll
    for (int ni = 0; ni < 4; ++ni) {
      int row = m0 + wr * 128 + mi * 16 + lr4;
      int col = n0 + wc * 64 + ni * 16 + lr16;
      size_t o = (size_t)bz * oBatch + (size_t)row * N + col;
      f32x4 v = acc[mi][ni];
      #pragma unroll
      for (int j = 0; j < 4; ++j) {
        size_t oo = o + (size_t)j * N;
        float x = v[j];
        if (EPI == 0) {
          outBf[oo] = f2bf(x * scale);
        } else if (EPI == 1) {
          outBf[oo] = f2bf(bf2f(auxBf[oo]) + x);
        } else if (EPI == 2) {
          float h = x + bias[col];
          h = h > 0.f ? h : 0.f;
          outBf[oo] = f2bf(h);
        } else {
          outF[oo] = x + bias[col] + bf2f(auxBf[oo]);
        }
      }
    }
  }
}

// ---------------- launch ----------------
extern "C" void kernel_launch(void* const* d_in, const int* in_sizes, int n_in,
                              void* d_out, int out_size, void* d_ws, size_t ws_size,
                              hipStream_t stream) {
  (void)in_sizes; (void)n_in; (void)out_size; (void)ws_size;
  const float* Q  = (const float*)d_in[0];
  const float* Km = (const float*)d_in[1];
  const float* V  = (const float*)d_in[2];
  const float* Vm = (const float*)d_in[3];
  const float* W1 = (const float*)d_in[4];
  const float* b1 = (const float*)d_in[5];
  const float* W2 = (const float*)d_in[6];
  const float* b2 = (const float*)d_in[7];
  float* out = (float*)d_out;

  const int LQ = 1024, LK = 1024, D = 1024;
  const size_t NQ = (size_t)32 * LQ * D;            // 33.5M elems

  // workspace layout (MiB offsets): Qb 0..64, Kb/hb 64..128, Vt 128..192,
  // Sb 192..256, P 256..320, Xb 320..384, W1b 384..386, W2b 386..388
  char* ws = (char*)d_ws;
  ushort* Qb  = (ushort*)(ws);
  ushort* Kb  = (ushort*)(ws + ((size_t)64 << 20));
  ushort* hb  = Kb;                                  // reuse (Kb dead after S-GEMM)
  ushort* Vt  = (ushort*)(ws + ((size_t)128 << 20));
  ushort* Sb  = (ushort*)(ws + ((size_t)192 << 20));
  ushort* P   = (ushort*)(ws + ((size_t)256 << 20));
  ushort* Xb  = (ushort*)(ws + ((size_t)320 << 20));
  ushort* W1b = (ushort*)(ws + ((size_t)384 << 20));
  ushort* W2b = (ushort*)(ws + ((size_t)386 << 20));

  const float inv_scale = 1.0f / (sqrtf(1024.0f) + 1e-8f);

  cast_f32_bf16<<<2048, 256, 0, stream>>>((const float4*)Q,  (ushort4*)Qb, (int)(NQ / 4));
  cast_f32_bf16<<<2048, 256, 0, stream>>>((const float4*)Km, (ushort4*)Kb, (int)(NQ / 4));
  cast_f32_bf16<<<256, 256, 0, stream>>>((const float4*)W1, (ushort4*)W1b, (1024 * 1024) / 4);
  cast_f32_bf16<<<256, 256, 0, stream>>>((const float4*)W2, (ushort4*)W2b, (1024 * 1024) / 4);
  transpose_cast_v<<<dim3(32, 32, 32), dim3(32, 8), 0, stream>>>(V, Vt);

  // Sb = bf16((Qb @ Kb^T) * inv_scale), batched over 32
  gemm256<0><<<dim3(4, 4, 32), 512, 0, stream>>>(
      Qb, Kb,
      (size_t)LQ * D, (size_t)LK * D, (size_t)LQ * LK,
      inv_scale, Sb, nullptr, nullptr, nullptr);

  softmax_mask<<<32768, 256, 0, stream>>>(Sb, P, Vm);

  // Xb = bf16(Qb + P @ V)
  gemm256<1><<<dim3(4, 4, 32), 512, 0, stream>>>(
      P, Vt,
      (size_t)LQ * LK, (size_t)D * LK, (size_t)LQ * D,
      1.f, Xb, nullptr, Qb, nullptr);

  // hb = bf16(relu(Xb @ W1^T + b1)); M = 32768 folded into blockIdx.y
  gemm256<2><<<dim3(4, 128, 1), 512, 0, stream>>>(
      Xb, W1b, 0, 0, 0,
      1.f, hb, nullptr, nullptr, b1);

  // out = hb @ W2^T + b2 + Xb
  gemm256<3><<<dim3(4, 128, 1), 512, 0, stream>>>(
      hb, W2b, 0, 0, 0,
      1.f, nullptr, out, Xb, b2);
}

// Round 9
// 536.368 us; speedup vs baseline: 1.0200x; 1.0198x over previous
//
#include <hip/hip_runtime.h>
#include <hip/hip_bf16.h>
#include <stdint.h>
#include <math.h>

// ---------------- types / helpers ----------------
typedef __attribute__((ext_vector_type(8))) short bf16x8;   // 8 bf16 in 4 VGPRs
typedef __attribute__((ext_vector_type(4))) float f32x4;

#define AS1 __attribute__((address_space(1)))
#define AS3 __attribute__((address_space(3)))

__device__ __forceinline__ ushort f2bf(float f) {
  union { float f; uint32_t u; } in; in.f = f;
  uint32_t u = in.u;
  uint32_t r = u + 0x7fffu + ((u >> 16) & 1u);   // RNE; inputs finite
  return (ushort)(r >> 16);
}
__device__ __forceinline__ float bf2f(ushort h) {
  union { uint32_t u; float f; } out; out.u = ((uint32_t)h) << 16;
  return out.f;
}

// ---------------- cast f32 -> bf16 (vectorized) ----------------
__global__ __launch_bounds__(256)
void cast_f32_bf16(const float4* __restrict__ in, ushort4* __restrict__ out, int n4) {
  int i = blockIdx.x * blockDim.x + threadIdx.x;
  int stride = gridDim.x * blockDim.x;
  for (; i < n4; i += stride) {
    float4 v = in[i];
    ushort4 o;
    o.x = f2bf(v.x); o.y = f2bf(v.y); o.z = f2bf(v.z); o.w = f2bf(v.w);
    out[i] = o;
  }
}

// ---------------- V (B,LK,D) f32 -> Vt (B,D,LK) bf16 ----------------
__global__ __launch_bounds__(256)
void transpose_cast_v(const float* __restrict__ V, ushort* __restrict__ Vt) {
  __shared__ ushort tile[32][33];                // +1 pad: no bank conflicts
  const int b  = blockIdx.z;
  const int k0 = blockIdx.x * 32;
  const int d0 = blockIdx.y * 32;
  const int tx = threadIdx.x;                    // 0..31
  const int ty = threadIdx.y;                    // 0..7
  const float* Vb = V + ((size_t)b * 1024 + k0) * 1024 + d0;
  #pragma unroll
  for (int r = 0; r < 4; ++r) {
    int k = ty * 4 + r;
    tile[k][tx] = f2bf(Vb[(size_t)k * 1024 + tx]);
  }
  __syncthreads();
  ushort* Vtb = Vt + ((size_t)b * 1024 + d0) * 1024 + k0;
  #pragma unroll
  for (int r = 0; r < 4; ++r) {
    int d = ty * 4 + r;
    Vtb[(size_t)d * 1024 + tx] = tile[tx][d];
  }
}

// ---------------- masked softmax over each (b,q) row of S (bf16 in/out) ----
__global__ __launch_bounds__(256)
void softmax_mask(const ushort* __restrict__ S, ushort* __restrict__ P,
                  const float* __restrict__ mask) {
  const int rowId = blockIdx.x;                  // 0..B*LQ-1
  const int b = rowId >> 10;                     // LQ = 1024
  const ushort4* srow = (const ushort4*)(S + (size_t)rowId * 1024);
  const float4* mrow = (const float4*)(mask + (size_t)b * 1024);
  const int t = threadIdx.x;
  const int wid = t >> 6, lane = t & 63;

  ushort4 sv = srow[t];
  float4 mv = mrow[t];
  float s[4] = {bf2f(sv.x), bf2f(sv.y), bf2f(sv.z), bf2f(sv.w)};
  float m[4] = {mv.x, mv.y, mv.z, mv.w};

  float mx = -INFINITY;
  #pragma unroll
  for (int i = 0; i < 4; ++i) if (m[i] != 0.f) mx = fmaxf(mx, s[i]);
  #pragma unroll
  for (int off = 32; off > 0; off >>= 1)
    mx = fmaxf(mx, __shfl_xor(mx, off));

  __shared__ float wred[4][2];
  if (lane == 0) wred[wid][0] = mx;
  __syncthreads();
  float M = fmaxf(fmaxf(wred[0][0], wred[1][0]), fmaxf(wred[2][0], wred[3][0]));

  float e[4]; float sum = 0.f;
  #pragma unroll
  for (int i = 0; i < 4; ++i) {
    e[i] = (m[i] != 0.f) ? __expf(s[i] - M) : 0.f;
    sum += e[i];
  }
  #pragma unroll
  for (int off = 32; off > 0; off >>= 1)
    sum += __shfl_xor(sum, off);
  if (lane == 0) wred[wid][1] = sum;
  __syncthreads();
  float Z = wred[0][1] + wred[1][1] + wred[2][1] + wred[3][1];
  float inv = (Z > 0.f) ? 1.f / Z : 0.f;

  ushort4 o;
  o.x = f2bf(e[0] * inv); o.y = f2bf(e[1] * inv);
  o.z = f2bf(e[2] * inv); o.w = f2bf(e[3] * inv);
  ((ushort4*)(P + (size_t)rowId * 1024))[t] = o;
}

// ---------------- GEMM 128x128, BK=64, 4 waves, single-buffer (m97) -------
// C = A(Mx1024,row) * Bt(1024x1024,row)^T.
// m97-exact structure: 32 KiB LDS, 2 barriers/K-tile, NO inline asm — the
// compiler emits vmcnt(0)/lgkmcnt(0) before each s_barrier itself.  The
// stall is hidden by CROSS-BLOCK overlap: __launch_bounds__(256,4) caps
// VGPR <=128 so ~4 blocks co-reside per CU (the m102/m132 lever: 1 block/CU
// = 320 TF, 3-4 blocks/CU = 833-874 TF on this same structure).
// + T2 swizzle (kills m98's 1.7e7 bank conflicts): byte involution
//   y ^= (y>>3)&0x70; rule #21: linear gload_lds dest + inverse-swizzled
//   global source + swizzled ds_read.
// + T1 XCD remap (all grids here are multiples of 8).
// EPI: 0 -> outBf = bf16(acc*scale)                              (S)
//      1 -> outBf = bf16(bf2f(auxBf) + acc)                      (X = Q + PV)
//      2 -> outBf = bf16(relu(acc + bias[col]))                  (FFN1 -> h)
//      3 -> outF  = acc + bias[col] + bf2f(auxBf)                (FFN2 + residual)
template<int EPI>
__global__ __launch_bounds__(256, 4)
void gemm128(const ushort* __restrict__ A, const ushort* __restrict__ Bt,
             size_t aBatch, size_t bBatch, size_t oBatch,
             float scale,
             ushort* outBf, float* outF, const ushort* auxBf,
             const float* __restrict__ bias)
{
  constexpr int K = 1024, N = 1024, NT = 16;    // K-tiles of 64
  __shared__ ushort lsA[128 * 64];              // 16 KiB
  __shared__ ushort lsB[128 * 64];              // 16 KiB
  const int t = threadIdx.x;
  const int w = t >> 6, lane = t & 63;
  const int wr = w >> 1, wc = w & 1;            // 2 x 2 waves -> 64x64 per wave
  const int lr16 = lane & 15, kg = lane >> 4;

  // T1: XCD-aware bijective remap (nwg is a multiple of 8 for all our grids)
  const unsigned nx = gridDim.x, ny = gridDim.y;
  unsigned flat = blockIdx.x + nx * (blockIdx.y + ny * blockIdx.z);
  const unsigned nwg = nx * ny * gridDim.z;
  const unsigned cpx = nwg >> 3;
  unsigned nf = (flat & 7u) * cpx + (flat >> 3);
  const unsigned bxi = nf % nx;
  const unsigned rest = nf / nx;
  const unsigned byi = rest % ny;
  const unsigned bz = rest / ny;
  const int m0 = byi * 128, n0 = bxi * 128;

  const char* Ab = (const char*)(A + (size_t)bz * aBatch + (size_t)m0 * K);
  const char* Bb = (const char*)(Bt + (size_t)bz * bBatch + (size_t)n0 * K);

  // staging decode: 4 chunks of 16B/lane per matrix per thread (16 KiB tile).
  // lds-linear byte y = (w*4+i)*1024 + lane*16; unswizzled tile byte
  // tb = y ^ ((y>>3)&0x70); global = (tb>>7)*2048 + (tb&127) + kt*128.
  int gOff[4], lOff[4];
  #pragma unroll
  for (int i = 0; i < 4; ++i) {
    int y = (w * 4 + i) * 1024 + lane * 16;
    int tb = y ^ ((y >> 3) & 0x70);
    gOff[i] = (tb >> 7) * 2048 + (tb & 127);
    lOff[i] = (w * 4 + i) * 1024;               // wave-uniform LDS base (+lane*16 by HW)
  }

  // fragment reads (swizzled): row*128 + ((ks*4+kg)^(row&7))*16, row&7 = lr16&7
  const int sl0 = (kg ^ (lr16 & 7)) << 4;
  const int aBase = (wr * 64 + lr16) * 128 + sl0;
  const int bBase = (wc * 64 + lr16) * 128 + sl0;

  f32x4 acc[4][4];
  #pragma unroll
  for (int i = 0; i < 4; ++i)
    #pragma unroll
    for (int j = 0; j < 4; ++j)
      acc[i][j] = (f32x4){0.f, 0.f, 0.f, 0.f};

  #pragma unroll 1
  for (int kt = 0; kt < NT; ++kt) {
    // stage tile kt into the single buffer (4+4 gload_lds w=16 per thread)
    #pragma unroll
    for (int i = 0; i < 4; ++i)
      __builtin_amdgcn_global_load_lds(
        (const AS1 void*)(Ab + gOff[i] + kt * 128),
        (AS3 void*)((char*)lsA + lOff[i]), 16, 0, 0);
    #pragma unroll
    for (int i = 0; i < 4; ++i)
      __builtin_amdgcn_global_load_lds(
        (const AS1 void*)(Bb + gOff[i] + kt * 128),
        (AS3 void*)((char*)lsB + lOff[i]), 16, 0, 0);
    __syncthreads();                            // compiler: vmcnt(0) drain

    #pragma unroll
    for (int ks = 0; ks < 2; ++ks) {
      bf16x8 af[4], bfv[4];
      #pragma unroll
      for (int mi = 0; mi < 4; ++mi)
        af[mi] = *(const bf16x8*)((const char*)lsA + ((aBase + mi * 2048) ^ (ks * 64)));
      #pragma unroll
      for (int ni = 0; ni < 4; ++ni)
        bfv[ni] = *(const bf16x8*)((const char*)lsB + ((bBase + ni * 2048) ^ (ks * 64)));
      #pragma unroll
      for (int mi = 0; mi < 4; ++mi)
        #pragma unroll
        for (int ni = 0; ni < 4; ++ni)
          acc[mi][ni] = __builtin_amdgcn_mfma_f32_16x16x32_bf16(
              af[mi], bfv[ni], acc[mi][ni], 0, 0, 0);
    }
    __syncthreads();                            // reads drained before re-stage
  }

  // epilogue: C/D layout col=lane&15, row=(lane>>4)*4+j  [m89-verified]
  const int lr4 = kg * 4;
  #pragma unroll
  for (int mi = 0; mi < 4; ++mi) {
    #pragma unroll
    for (int ni = 0; ni < 4; ++ni) {
      int row = m0 + wr * 64 + mi * 16 + lr4;
      int col = n0 + wc * 64 + ni * 16 + lr16;
      size_t o = (size_t)bz * oBatch + (size_t)row * N + col;
      f32x4 v = acc[mi][ni];
      #pragma unroll
      for (int j = 0; j < 4; ++j) {
        size_t oo = o + (size_t)j * N;
        float x = v[j];
        if (EPI == 0) {
          outBf[oo] = f2bf(x * scale);
        } else if (EPI == 1) {
          outBf[oo] = f2bf(bf2f(auxBf[oo]) + x);
        } else if (EPI == 2) {
          float h = x + bias[col];
          h = h > 0.f ? h : 0.f;
          outBf[oo] = f2bf(h);
        } else {
          outF[oo] = x + bias[col] + bf2f(auxBf[oo]);
        }
      }
    }
  }
}

// ---------------- launch ----------------
extern "C" void kernel_launch(void* const* d_in, const int* in_sizes, int n_in,
                              void* d_out, int out_size, void* d_ws, size_t ws_size,
                              hipStream_t stream) {
  (void)in_sizes; (void)n_in; (void)out_size; (void)ws_size;
  const float* Q  = (const float*)d_in[0];
  const float* Km = (const float*)d_in[1];
  const float* V  = (const float*)d_in[2];
  const float* Vm = (const float*)d_in[3];
  const float* W1 = (const float*)d_in[4];
  const float* b1 = (const float*)d_in[5];
  const float* W2 = (const float*)d_in[6];
  const float* b2 = (const float*)d_in[7];
  float* out = (float*)d_out;

  const int LQ = 1024, LK = 1024, D = 1024;
  const size_t NQ = (size_t)32 * LQ * D;            // 33.5M elems

  // workspace layout (MiB offsets): Qb 0..64, Kb/hb 64..128, Vt 128..192,
  // Sb 192..256, P 256..320, Xb 320..384, W1b 384..386, W2b 386..388
  char* ws = (char*)d_ws;
  ushort* Qb  = (ushort*)(ws);
  ushort* Kb  = (ushort*)(ws + ((size_t)64 << 20));
  ushort* hb  = Kb;                                  // reuse (Kb dead after S-GEMM)
  ushort* Vt  = (ushort*)(ws + ((size_t)128 << 20));
  ushort* Sb  = (ushort*)(ws + ((size_t)192 << 20));
  ushort* P   = (ushort*)(ws + ((size_t)256 << 20));
  ushort* Xb  = (ushort*)(ws + ((size_t)320 << 20));
  ushort* W1b = (ushort*)(ws + ((size_t)384 << 20));
  ushort* W2b = (ushort*)(ws + ((size_t)386 << 20));

  const float inv_scale = 1.0f / (sqrtf(1024.0f) + 1e-8f);

  cast_f32_bf16<<<2048, 256, 0, stream>>>((const float4*)Q,  (ushort4*)Qb, (int)(NQ / 4));
  cast_f32_bf16<<<2048, 256, 0, stream>>>((const float4*)Km, (ushort4*)Kb, (int)(NQ / 4));
  cast_f32_bf16<<<256, 256, 0, stream>>>((const float4*)W1, (ushort4*)W1b, (1024 * 1024) / 4);
  cast_f32_bf16<<<256, 256, 0, stream>>>((const float4*)W2, (ushort4*)W2b, (1024 * 1024) / 4);
  transpose_cast_v<<<dim3(32, 32, 32), dim3(32, 8), 0, stream>>>(V, Vt);

  // Sb = bf16((Qb @ Kb^T) * inv_scale), batched over 32
  gemm128<0><<<dim3(8, 8, 32), 256, 0, stream>>>(
      Qb, Kb,
      (size_t)LQ * D, (size_t)LK * D, (size_t)LQ * LK,
      inv_scale, Sb, nullptr, nullptr, nullptr);

  softmax_mask<<<32768, 256, 0, stream>>>(Sb, P, Vm);

  // Xb = bf16(Qb + P @ V)
  gemm128<1><<<dim3(8, 8, 32), 256, 0, stream>>>(
      P, Vt,
      (size_t)LQ * LK, (size_t)D * LK, (size_t)LQ * D,
      1.f, Xb, nullptr, Qb, nullptr);

  // hb = bf16(relu(Xb @ W1^T + b1)); M = 32768 folded into blockIdx.y
  gemm128<2><<<dim3(8, 256, 1), 256, 0, stream>>>(
      Xb, W1b, 0, 0, 0,
      1.f, hb, nullptr, nullptr, b1);

  // out = hb @ W2^T + b2 + Xb
  gemm128<3><<<dim3(8, 256, 1), 256, 0, stream>>>(
      hb, W2b, 0, 0, 0,
      1.f, nullptr, out, Xb, b2);
}